// Round 15
// baseline (303.699 us; speedup 1.0000x reference)
//
#include <hip/hip_runtime.h>

#define T_LEN 256
#define D_IN 4
#define SPR 4                       // timesteps per barrier round
#define NROUND (T_LEN / SPR + 2)    // 66: layer skew 0..2

typedef __fp16 h4 __attribute__((ext_vector_type(4)));
typedef __fp16 cvt2_t __attribute__((ext_vector_type(2)));
typedef float float4v __attribute__((ext_vector_type(4)));

struct CellW { const float *Wih, *Whh, *bih, *bhh; };
struct Params {
    CellW c[6];
    const float* y;
    const float* Wout;
    const float* bout;
    float* out;
};

__device__ __forceinline__ float fexp2(float x) { return __builtin_amdgcn_exp2f(x); }
__device__ __forceinline__ float frcp(float x)  { return __builtin_amdgcn_rcpf(x); }
__device__ __forceinline__ int packh(float a, float b) {
    cvt2_t p = __builtin_amdgcn_cvt_pkrtz(a, b);
    return __builtin_bit_cast(int, p);
}
__device__ __forceinline__ h4 mk(int lo, int hi) {
    int2 v; v.x = lo; v.y = hi;
    return __builtin_bit_cast(h4, v);
}

// K=16 MFMA: B-layout == D-layout (lane(n,Q): B k=4Q..4Q+3 / D rows 4Q..4Q+3,
// col n) -> recurrence B operand is the packed act output, zero movement.
#define MFMA16(a, b, c) __builtin_amdgcn_mfma_f32_16x16x16f16(a, b, c, 0, 0, 0)

// r13's verified paired-rcp activation: 5 exp + 3 rcp (passed @1.95e-3).
// pi,pf,po pre-scaled by -log2e; pg by -2log2e (folded into A/bias).
__device__ __forceinline__ float act_one(float pi, float pf, float pg, float po,
                                         float& c) {
    float ei = fexp2(pi);
    float ef = fexp2(pf);
    float eg = fexp2(pg);
    float f  = frcp(1.f + ef);
    float ig = (1.f - eg) * frcp((1.f + ei) * (1.f + eg));
    float cn = fmaf(f, c, ig);
    c = cn;
    float eo = fexp2(po);
    float ec = fexp2(fminf(cn * -2.8853900817779268f, 80.f));
    return (1.f - ec) * frcp((1.f + eo) * (1.f + ec));
}

// Block = 3 waves = 3 layers; each wave runs TWO tiles (dir0+dir1 of the same
// 16 chains) for compiler-scheduled ILP (two independent chains per wave).
// Cross-layer h: per-lane int2 copy via parity LDS slabs, barrier per round
// (r13 discipline — no ring). Output projection fused as 2 MFMAs on wave 2.
__global__ void __launch_bounds__(192)
__attribute__((amdgpu_waves_per_eu(1, 2)))
lstm_chain_kernel(Params p)
{
    __shared__ int2 lds_h[2][2][2][SPR][64];   // [tile][producer][parity][k][lane] 8KB

    const int w = threadIdx.x >> 6;     // wave = layer
    const int L = threadIdx.x & 63;
    const int n = L & 15;               // batch col
    const int Q = L >> 4;
    const int b0 = blockIdx.x * 16;

    const float LOG2E = 1.4426950408889634f;

    // ---- A-frags (m=n, k=4Q..4Q+3) + bias for both dirs, scale folded ----
    h4 AihA[4], AhhA[4], AihB[4], AhhB[4];
    float4v bsA[4], bsB[4];
#pragma unroll
    for (int d = 0; d < 2; ++d) {
        const CellW cw = p.c[d * 3 + w];
#pragma unroll
        for (int g = 0; g < 4; ++g) {
            const float s = (g == 2) ? -2.f * LOG2E : -LOG2E;
            const int row = g * 16 + n;
            float vi[4], vh[4];
#pragma unroll
            for (int i = 0; i < 4; ++i) {
                const int k = 4 * Q + i;
                vi[i] = (w == 0) ? ((Q == 0) ? cw.Wih[row * D_IN + k] : 0.f)
                                 : cw.Wih[row * 16 + k];
                vh[i] = cw.Whh[row * 16 + k];
            }
            h4 ai = mk(packh(vi[0] * s, vi[1] * s), packh(vi[2] * s, vi[3] * s));
            h4 ah = mk(packh(vh[0] * s, vh[1] * s), packh(vh[2] * s, vh[3] * s));
            const int u0 = g * 16 + 4 * Q;
            float4 bi = *(const float4*)&cw.bih[u0];
            float4 bh = *(const float4*)&cw.bhh[u0];
            float4v bsv = (float4v){(bi.x+bh.x)*s, (bi.y+bh.y)*s,
                                    (bi.z+bh.z)*s, (bi.w+bh.w)*s};
            if (d == 0) { AihA[g] = ai; AhhA[g] = ah; bsA[g] = bsv; }
            else        { AihB[g] = ai; AhhB[g] = ah; bsB[g] = bsv; }
        }
    }

    // ---- x prefetch (wave 0, lanes L<16 = chain n), both dirs ----
    const float* ybase = p.y + (size_t)b0 * (T_LEN * D_IN);
    float4 xnA[SPR], xnB[SPR];
    if (w == 0 && L < 16) {
#pragma unroll
        for (int k = 0; k < SPR; ++k) {
            xnA[k] = *(const float4*)(ybase + ((size_t)n * T_LEN + k) * D_IN);
            xnB[k] = *(const float4*)(ybase + ((size_t)n * T_LEN + (T_LEN - 1 - k)) * D_IN);
        }
    }

    float ccA[4] = {0.f,0.f,0.f,0.f}, ccB[4] = {0.f,0.f,0.f,0.f};
    float hA[4], hB[4];
    int hpA0 = 0, hpA1 = 0, hpB0 = 0, hpB1 = 0;

#pragma unroll 1
    for (int s = 0; s < NROUND; ++s) {
        __syncthreads();
        const int t0 = (s - w) * SPR;
        if (t0 < 0 || t0 >= T_LEN) continue;

        // wave 0: commit prefetched x, start next round's loads
        int xpA[SPR][2], xpB[SPR][2];
        if (w == 0) {
            if (L < 16) {
#pragma unroll
                for (int k = 0; k < SPR; ++k) {
                    xpA[k][0] = packh(xnA[k].x, xnA[k].y);
                    xpA[k][1] = packh(xnA[k].z, xnA[k].w);
                    xpB[k][0] = packh(xnB[k].x, xnB[k].y);
                    xpB[k][1] = packh(xnB[k].z, xnB[k].w);
                }
                if (t0 + SPR < T_LEN) {
#pragma unroll
                    for (int k = 0; k < SPR; ++k) {
                        const int t = t0 + SPR + k;
                        xnA[k] = *(const float4*)(ybase + ((size_t)n * T_LEN + t) * D_IN);
                        xnB[k] = *(const float4*)(ybase + ((size_t)n * T_LEN + (T_LEN - 1 - t)) * D_IN);
                    }
                }
            } else {
#pragma unroll
                for (int k = 0; k < SPR; ++k) {
                    xpA[k][0] = 0; xpA[k][1] = 0;
                    xpB[k][0] = 0; xpB[k][1] = 0;
                }
            }
        }

        // hoist cross-layer h reads for both tiles (written at round s-1)
        int2 hvA[SPR], hvB[SPR];
        if (w >= 1) {
#pragma unroll
            for (int k = 0; k < SPR; ++k) {
                hvA[k] = lds_h[0][w - 1][(s + 1) & 1][k][L];
                hvB[k] = lds_h[1][w - 1][(s + 1) & 1][k][L];
            }
        }

#pragma unroll
        for (int k = 0; k < SPR; ++k) {
            // ---- tile A (dir 0) ----
            {
                h4 bin = (w == 0) ? mk(xpA[k][0], xpA[k][1]) : mk(hvA[k].x, hvA[k].y);
                h4 bh  = mk(hpA0, hpA1);
                float4v pi = MFMA16(AhhA[0], bh, MFMA16(AihA[0], bin, bsA[0]));
                float4v pf = MFMA16(AhhA[1], bh, MFMA16(AihA[1], bin, bsA[1]));
                float4v pg = MFMA16(AhhA[2], bh, MFMA16(AihA[2], bin, bsA[2]));
                float4v po = MFMA16(AhhA[3], bh, MFMA16(AihA[3], bin, bsA[3]));
                hA[0] = act_one(pi[0], pf[0], pg[0], po[0], ccA[0]);
                hA[1] = act_one(pi[1], pf[1], pg[1], po[1], ccA[1]);
                hA[2] = act_one(pi[2], pf[2], pg[2], po[2], ccA[2]);
                hA[3] = act_one(pi[3], pf[3], pg[3], po[3], ccA[3]);
                hpA0 = packh(hA[0], hA[1]);
                hpA1 = packh(hA[2], hA[3]);
            }
            // ---- tile B (dir 1) ----
            {
                h4 bin = (w == 0) ? mk(xpB[k][0], xpB[k][1]) : mk(hvB[k].x, hvB[k].y);
                h4 bh  = mk(hpB0, hpB1);
                float4v pi = MFMA16(AhhB[0], bh, MFMA16(AihB[0], bin, bsB[0]));
                float4v pf = MFMA16(AhhB[1], bh, MFMA16(AihB[1], bin, bsB[1]));
                float4v pg = MFMA16(AhhB[2], bh, MFMA16(AihB[2], bin, bsB[2]));
                float4v po = MFMA16(AhhB[3], bh, MFMA16(AihB[3], bin, bsB[3]));
                hB[0] = act_one(pi[0], pf[0], pg[0], po[0], ccB[0]);
                hB[1] = act_one(pi[1], pf[1], pg[1], po[1], ccB[1]);
                hB[2] = act_one(pi[2], pf[2], pg[2], po[2], ccB[2]);
                hB[3] = act_one(pi[3], pf[3], pg[3], po[3], ccB[3]);
                hpB0 = packh(hB[0], hB[1]);
                hpB1 = packh(hB[2], hB[3]);
            }
            if (w < 2) {
                int2 ha; ha.x = hpA0; ha.y = hpA1;
                int2 hb; hb.x = hpB0; hb.y = hpB1;
                lds_h[0][w][s & 1][k][L] = ha;
                lds_h[1][w][s & 1][k][L] = hb;
            }
        }
    }

    // ---- fused output projection (wave 2 holds h3 of both dirs) ----
    // out[b][o] = sum_m hf3[b][m]*Wout[o][m] + hb3[b][m]*Wout[o][16+m] + bout[o]
    // A_out[m=o][k=unit] nonzero only for m<4; D rows 4Q+r -> Q==0 lanes hold
    // out[o=r][batch n].
    if (w == 2) {
        float vF[4], vB[4];
#pragma unroll
        for (int i = 0; i < 4; ++i) {
            const int k = 4 * Q + i;
            vF[i] = (n < 4) ? p.Wout[n * 32 + k]      : 0.f;
            vB[i] = (n < 4) ? p.Wout[n * 32 + 16 + k] : 0.f;
        }
        h4 aF = mk(packh(vF[0], vF[1]), packh(vF[2], vF[3]));
        h4 aB = mk(packh(vB[0], vB[1]), packh(vB[2], vB[3]));
        float4v bsE = {0.f, 0.f, 0.f, 0.f};
        if (Q == 0) {
            float4 bo = *(const float4*)p.bout;
            bsE = (float4v){bo.x, bo.y, bo.z, bo.w};
        }
        float4v d = MFMA16(aF, mk(hpA0, hpA1), bsE);
        d = MFMA16(aB, mk(hpB0, hpB1), d);
        if (L < 16)
            *(float4v*)&p.out[(size_t)(b0 + n) * 4] = d;
    }
}

extern "C" void kernel_launch(void* const* d_in, const int* in_sizes, int n_in,
                              void* d_out, int out_size, void* d_ws, size_t ws_size,
                              hipStream_t stream)
{
    const int B = in_sizes[0] / (T_LEN * D_IN); // 4096

    Params p;
    for (int s = 0; s < 6; ++s) {
        p.c[s].Wih = (const float*)d_in[1 + 4 * s];
        p.c[s].Whh = (const float*)d_in[2 + 4 * s];
        p.c[s].bih = (const float*)d_in[3 + 4 * s];
        p.c[s].bhh = (const float*)d_in[4 + 4 * s];
    }
    p.y = (const float*)d_in[0];
    p.Wout = (const float*)d_in[25];
    p.bout = (const float*)d_in[26];
    p.out = (float*)d_out;

    const int blocks = B / 16;               // 256: one block per 16 chains, both dirs
    lstm_chain_kernel<<<blocks, 192, 0, stream>>>(p);
}